// Round 6
// baseline (2118.470 us; speedup 1.0000x reference)
//
#include <hip/hip_runtime.h>

#define NN 50000
#define NE 1600000
#define C 64            // NOPEN == NUM_OUTPUT == 64
#define NIN 16
#define DTH 0.025f      // dt*H = (1.0/4)*0.1
#define NB 782          // buckets of 64 nodes: ceil(50000/64)

union PK2 { uint32_t u; _Float16 h[2]; };

// ---- setup: transposes (fp32) ----
__global__ void k_setup(const float* __restrict__ KN1, const float* __restrict__ KNc,
                        const float* __restrict__ K1,
                        float* __restrict__ KN1T, float* __restrict__ KNcT,
                        float* __restrict__ K1T) {
    for (int idx = threadIdx.x; idx < C * C; idx += blockDim.x) {
        int o = idx >> 6, i = idx & 63;
        KN1T[i * C + o] = KN1[o * C + i];   // [i][o] = KN1[o][i]
        KNcT[i * C + o] = KNc[o * C + i];   // [i][o] = KNclose[o][i]
    }
    for (int idx = threadIdx.x; idx < C * NIN; idx += blockDim.x) {
        int o = idx >> 4, i = idx & 15;
        K1T[i * C + o] = K1[o * NIN + i];   // [i][o] = K1[o][i]
    }
}

// ---- degree / counts ----
__global__ void k_zero_cnt(int* __restrict__ cnt, int* __restrict__ degj) {
    int n = blockIdx.x * blockDim.x + threadIdx.x;
    if (n < NN) { cnt[n] = 0; degj[n] = 1; }          // self loop in degree
}
__global__ void k_count(const int* __restrict__ iInd, const int* __restrict__ jInd,
                        int* __restrict__ cnt, int* __restrict__ degj) {
    int e = blockIdx.x * blockDim.x + threadIdx.x;
    if (e < NE) {
        int i = iInd[e], j = jInd[e];
        atomicAdd(&cnt[i], 1);
        atomicAdd(&cnt[j], 1);
        atomicAdd(&degj[j], 1);
    }
}
__global__ void k_dinv(const int* __restrict__ degj, float* __restrict__ dinv) {
    int n = blockIdx.x * blockDim.x + threadIdx.x;
    if (n < NN) dinv[n] = 1.0f / sqrtf((float)degj[n]);
}

// blocked single-block scan: 1024 threads x 49 nodes each
#define NPT 49
__global__ void k_scan(const int* __restrict__ cnt, int* __restrict__ rowptr) {
    __shared__ int tmp[1024];
    int tid = threadIdx.x;
    int base = tid * NPT;
    int s = 0;
    for (int i = 0; i < NPT; i++) { int n = base + i; if (n < NN) s += cnt[n]; }
    tmp[tid] = s;
    __syncthreads();
    for (int off = 1; off < 1024; off <<= 1) {
        int a = (tid >= off) ? tmp[tid - off] : 0;
        __syncthreads();
        tmp[tid] += a;
        __syncthreads();
    }
    int excl = tmp[tid] - s;
    for (int i = 0; i < NPT; i++) {
        int n = base + i;
        if (n < NN) { rowptr[n] = excl; excl += cnt[n]; }
    }
    if (tid == 1023) rowptr[NN] = excl;   // base >= NN -> excl == grand total
}
__global__ void k_binit(const int* __restrict__ rowptr, int* __restrict__ bcur) {
    int b = blockIdx.x * blockDim.x + threadIdx.x;
    if (b < NB) bcur[b] = rowptr[b * 64];
}

// ---- phase A: append (target|sign, other) to the target's bucket stream ----
__global__ void k_fillA(const int* __restrict__ iInd, const int* __restrict__ jInd,
                        int* __restrict__ bcur, uint2* __restrict__ stg) {
    int e = blockIdx.x * blockDim.x + threadIdx.x;
    if (e < NE) {
        int i = iInd[e], j = jInd[e];
        int p = atomicAdd(&bcur[i >> 6], 1);
        stg[p] = make_uint2((unsigned)i, (unsigned)j);                 // sign 0: target=i
        p = atomicAdd(&bcur[j >> 6], 1);
        stg[p] = make_uint2((unsigned)j | 0x80000000u, (unsigned)i);   // sign 1: target=j
    }
}
// ---- phase B: per-bucket local counting sort -> final adj (other, +-w) ----
__launch_bounds__(256)
__global__ void k_fillB(const int* __restrict__ rowptr, const uint2* __restrict__ stg,
                        const float* __restrict__ dinv, uint2* __restrict__ adj) {
    __shared__ int lcur[64];
    int b = blockIdx.x;
    int n0 = b * 64;
    int tid = threadIdx.x;
    if (tid < 64) {
        int n = n0 + tid;
        lcur[tid] = (n < NN) ? rowptr[n] : 0;
    }
    __syncthreads();
    int base = rowptr[n0];
    int hi = n0 + 64; if (hi > NN) hi = NN;
    int endv = rowptr[hi];
    for (int t = base + tid; t < endv; t += 256) {
        uint2 s = stg[t];
        int target = (int)(s.x & 0x7FFFFFFFu);
        int sign = (int)(s.x >> 31);
        int other = (int)s.y;
        int p = atomicAdd(&lcur[target - n0], 1);
        float a = dinv[target] * dinv[other];
        if (sign) a = -a;
        adj[p] = make_uint2((unsigned)other, __float_as_uint(a));
    }
}

// ---- opening: x = relu(K1*xn); u0 = KN1*x (f16) ----
__launch_bounds__(256)
__global__ void k_open_u(const float* __restrict__ xn, const float* __restrict__ K1T,
                         const float* __restrict__ KN1T,
                         float* __restrict__ x, _Float16* __restrict__ u0) {
    __shared__ float sK1T[NIN * C];
    __shared__ float sKT[C * C];
    for (int idx = threadIdx.x; idx < NIN * C; idx += 256) sK1T[idx] = K1T[idx];
    for (int idx = threadIdx.x; idx < C * C; idx += 256) sKT[idx] = KN1T[idx];
    __syncthreads();
    int wv = threadIdx.x >> 6, lane = threadIdx.x & 63;
    int n = blockIdx.x * 4 + wv;
    float acc = 0.f;
#pragma unroll
    for (int i = 0; i < NIN; i++)
        acc = fmaf(sK1T[i * C + lane], xn[i * NN + n], acc);
    float xr = fmaxf(acc, 0.f);
    x[n * C + lane] = xr;
    float ua = 0.f;
    for (int i = 0; i < C; i++)
        ua = fmaf(sKT[i * C + lane], __shfl(xr, i, 64), ua);
    u0[n * C + lane] = (_Float16)ua;
}

// ---- per-layer fused kernel (layers 0..2):
//   s_n = sum_adj a*relu(a*(u_n - u_other));  x -= dtH*(KN1^T s);  unext = KN1*x
__launch_bounds__(256)
__global__ void k_glayer(const int* __restrict__ rowptr, const uint2* __restrict__ adj,
                         const _Float16* __restrict__ ucur,
                         const float* __restrict__ KN1, const float* __restrict__ KN1T,
                         float* __restrict__ x, _Float16* __restrict__ unext) {
    __shared__ float sM[C * C];    // raw KN1 [i*C+o] -> d[o] = sum_i KN1[i,o] s[i]
    __shared__ float sKT[C * C];   // KN1T [i*C+o]   -> u[o] = sum_i KN1[o,i] x[i]
    for (int idx = threadIdx.x; idx < C * C; idx += 256) { sM[idx] = KN1[idx]; sKT[idx] = KN1T[idx]; }
    __syncthreads();
    int wv = threadIdx.x >> 6, lane = threadIdx.x & 63;
    int n = blockIdx.x * 4 + wv;
    const int grp = lane >> 5, cp = lane & 31;
    const uint32_t* up = (const uint32_t*)ucur;   // 32 f16x2 per node row
    PK2 pn; pn.u = up[n * 32 + cp];
    float unx = (float)pn.h[0], uny = (float)pn.h[1];
    int k = rowptr[n], e1 = rowptr[n + 1];
    float ax = 0.f, ay = 0.f;
    for (; k + 4 <= e1; k += 4) {
        uint2 e0 = adj[k + grp];
        uint2 e2 = adj[k + 2 + grp];
        uint32_t q0 = up[(size_t)e0.x * 32 + cp];
        uint32_t q1 = up[(size_t)e2.x * 32 + cp];
        float a0 = __uint_as_float(e0.y), a1 = __uint_as_float(e2.y);
        PK2 c0, c1; c0.u = q0; c1.u = q1;
        ax = fmaf(a0, fmaxf(a0 * (unx - (float)c0.h[0]), 0.f), ax);
        ay = fmaf(a0, fmaxf(a0 * (uny - (float)c0.h[1]), 0.f), ay);
        ax = fmaf(a1, fmaxf(a1 * (unx - (float)c1.h[0]), 0.f), ax);
        ay = fmaf(a1, fmaxf(a1 * (uny - (float)c1.h[1]), 0.f), ay);
    }
    for (; k + 2 <= e1; k += 2) {
        uint2 e0 = adj[k + grp];
        uint32_t q0 = up[(size_t)e0.x * 32 + cp];
        float a0 = __uint_as_float(e0.y);
        PK2 c0; c0.u = q0;
        ax = fmaf(a0, fmaxf(a0 * (unx - (float)c0.h[0]), 0.f), ax);
        ay = fmaf(a0, fmaxf(a0 * (uny - (float)c0.h[1]), 0.f), ay);
    }
    if (k < e1 && grp == 0) {
        uint2 e0 = adj[k];
        uint32_t q0 = up[(size_t)e0.x * 32 + cp];
        float a0 = __uint_as_float(e0.y);
        PK2 c0; c0.u = q0;
        ax = fmaf(a0, fmaxf(a0 * (unx - (float)c0.h[0]), 0.f), ax);
        ay = fmaf(a0, fmaxf(a0 * (uny - (float)c0.h[1]), 0.f), ay);
    }
    ax += __shfl_xor(ax, 32, 64);
    ay += __shfl_xor(ay, 32, 64);
    float lowv = __shfl(ax, lane >> 1, 64);
    float highv = __shfl(ay, lane >> 1, 64);
    float sc = (lane & 1) ? highv : lowv;          // lane = channel now
    float dacc = 0.f;
    for (int i = 0; i < C; i++)
        dacc = fmaf(sM[i * C + lane], __shfl(sc, i, 64), dacc);
    float xnew = fmaf(-DTH, dacc, x[n * C + lane]);
    x[n * C + lane] = xnew;
    float ua = 0.f;
    for (int i = 0; i < C; i++)
        ua = fmaf(sKT[i * C + lane], __shfl(xnew, i, 64), ua);
    unext[n * C + lane] = (_Float16)ua;
}

// ---- final layer: same gather core, epilogue = KNclose + log_softmax ----
__launch_bounds__(256)
__global__ void k_gclose(const int* __restrict__ rowptr, const uint2* __restrict__ adj,
                         const _Float16* __restrict__ ucur,
                         const float* __restrict__ KN1, const float* __restrict__ KNcT,
                         const float* __restrict__ x, float* __restrict__ out) {
    __shared__ float sM[C * C];    // raw KN1
    __shared__ float sKc[C * C];   // KNcT
    for (int idx = threadIdx.x; idx < C * C; idx += 256) { sM[idx] = KN1[idx]; sKc[idx] = KNcT[idx]; }
    __syncthreads();
    int wv = threadIdx.x >> 6, lane = threadIdx.x & 63;
    int n = blockIdx.x * 4 + wv;
    const int grp = lane >> 5, cp = lane & 31;
    const uint32_t* up = (const uint32_t*)ucur;
    PK2 pn; pn.u = up[n * 32 + cp];
    float unx = (float)pn.h[0], uny = (float)pn.h[1];
    int k = rowptr[n], e1 = rowptr[n + 1];
    float ax = 0.f, ay = 0.f;
    for (; k + 4 <= e1; k += 4) {
        uint2 e0 = adj[k + grp];
        uint2 e2 = adj[k + 2 + grp];
        uint32_t q0 = up[(size_t)e0.x * 32 + cp];
        uint32_t q1 = up[(size_t)e2.x * 32 + cp];
        float a0 = __uint_as_float(e0.y), a1 = __uint_as_float(e2.y);
        PK2 c0, c1; c0.u = q0; c1.u = q1;
        ax = fmaf(a0, fmaxf(a0 * (unx - (float)c0.h[0]), 0.f), ax);
        ay = fmaf(a0, fmaxf(a0 * (uny - (float)c0.h[1]), 0.f), ay);
        ax = fmaf(a1, fmaxf(a1 * (unx - (float)c1.h[0]), 0.f), ax);
        ay = fmaf(a1, fmaxf(a1 * (uny - (float)c1.h[1]), 0.f), ay);
    }
    for (; k + 2 <= e1; k += 2) {
        uint2 e0 = adj[k + grp];
        uint32_t q0 = up[(size_t)e0.x * 32 + cp];
        float a0 = __uint_as_float(e0.y);
        PK2 c0; c0.u = q0;
        ax = fmaf(a0, fmaxf(a0 * (unx - (float)c0.h[0]), 0.f), ax);
        ay = fmaf(a0, fmaxf(a0 * (uny - (float)c0.h[1]), 0.f), ay);
    }
    if (k < e1 && grp == 0) {
        uint2 e0 = adj[k];
        uint32_t q0 = up[(size_t)e0.x * 32 + cp];
        float a0 = __uint_as_float(e0.y);
        PK2 c0; c0.u = q0;
        ax = fmaf(a0, fmaxf(a0 * (unx - (float)c0.h[0]), 0.f), ax);
        ay = fmaf(a0, fmaxf(a0 * (uny - (float)c0.h[1]), 0.f), ay);
    }
    ax += __shfl_xor(ax, 32, 64);
    ay += __shfl_xor(ay, 32, 64);
    float lowv = __shfl(ax, lane >> 1, 64);
    float highv = __shfl(ay, lane >> 1, 64);
    float sc = (lane & 1) ? highv : lowv;
    float dacc = 0.f;
    for (int i = 0; i < C; i++)
        dacc = fmaf(sM[i * C + lane], __shfl(sc, i, 64), dacc);
    float xnew = fmaf(-DTH, dacc, x[n * C + lane]);
    float o = 0.f;
    for (int i = 0; i < C; i++)
        o = fmaf(sKc[i * C + lane], __shfl(xnew, i, 64), o);
    float m = o;
#pragma unroll
    for (int off = 32; off; off >>= 1) m = fmaxf(m, __shfl_xor(m, off, 64));
    float sum = expf(o - m);
#pragma unroll
    for (int off = 32; off; off >>= 1) sum += __shfl_xor(sum, off, 64);
    out[n * C + lane] = o - m - logf(sum);
}

extern "C" void kernel_launch(void* const* d_in, const int* in_sizes, int n_in,
                              void* d_out, int out_size, void* d_ws, size_t ws_size,
                              hipStream_t stream) {
    (void)in_sizes; (void)n_in; (void)out_size; (void)ws_size;
    const float* xn   = (const float*)d_in[0];
    const int* iInd   = (const int*)d_in[1];
    const int* jInd   = (const int*)d_in[2];
    // d_in[3] = n_nodes scalar (fixed 50000)
    const float* K1   = (const float*)d_in[4];
    const float* KN1  = (const float*)d_in[5];
    const float* KNc  = (const float*)d_in[6];
    float* out = (float*)d_out;

    char* base = (char*)d_ws;
    size_t off = 0;
    auto alloc = [&](size_t bytes) { char* p = base + off; off = (off + bytes + 255) & ~(size_t)255; return p; };
    float* KN1T = (float*)alloc(C * C * 4);
    float* KNcT = (float*)alloc(C * C * 4);
    float* K1T  = (float*)alloc(NIN * C * 4);
    int* degj   = (int*)alloc(NN * 4);
    int* cnt    = (int*)alloc(NN * 4);
    int* rowptr = (int*)alloc((NN + 1) * 4);
    int* bcur   = (int*)alloc(NB * 4);
    float* dinv = (float*)alloc(NN * 4);
    float* x    = (float*)alloc((size_t)NN * C * 4);       // 12.8 MB
    _Float16* ua = (_Float16*)alloc((size_t)NN * C * 2);   // 6.4 MB
    _Float16* ub = (_Float16*)alloc((size_t)NN * C * 2);   // 6.4 MB
    uint2* stg  = (uint2*)alloc((size_t)2 * NE * 8);       // 25.6 MB
    uint2* adj  = (uint2*)alloc((size_t)2 * NE * 8);       // 25.6 MB

    // prolog: transposes, degrees, CSR adjacency (bucketed two-phase fill)
    k_setup<<<1, 256, 0, stream>>>(KN1, KNc, K1, KN1T, KNcT, K1T);
    k_zero_cnt<<<(NN + 255) / 256, 256, 0, stream>>>(cnt, degj);
    k_count<<<NE / 256, 256, 0, stream>>>(iInd, jInd, cnt, degj);
    k_dinv<<<(NN + 255) / 256, 256, 0, stream>>>(degj, dinv);
    k_scan<<<1, 1024, 0, stream>>>(cnt, rowptr);
    k_binit<<<(NB + 255) / 256, 256, 0, stream>>>(rowptr, bcur);
    k_fillA<<<NE / 256, 256, 0, stream>>>(iInd, jInd, bcur, stg);
    k_fillB<<<NB, 256, 0, stream>>>(rowptr, stg, dinv, adj);

    // opening + u0
    k_open_u<<<NN / 4, 256, 0, stream>>>(xn, K1T, KN1T, x, ua);

    // 4 layers: fused gather + KN1^T + update + next-u (double-buffered u)
    k_glayer<<<NN / 4, 256, 0, stream>>>(rowptr, adj, ua, KN1, KN1T, x, ub);
    k_glayer<<<NN / 4, 256, 0, stream>>>(rowptr, adj, ub, KN1, KN1T, x, ua);
    k_glayer<<<NN / 4, 256, 0, stream>>>(rowptr, adj, ua, KN1, KN1T, x, ub);
    k_gclose<<<NN / 4, 256, 0, stream>>>(rowptr, adj, ub, KN1, KNcT, x, out);
}

// Round 7
// 1330.103 us; speedup vs baseline: 1.5927x; 1.5927x over previous
//
#include <hip/hip_runtime.h>

#define NN 50000
#define NE 1600000
#define C 64            // NOPEN == NUM_OUTPUT == 64
#define NIN 16
#define DTH 0.025f      // dt*H = (1.0/4)*0.1

union PK2 { uint32_t u; _Float16 h[2]; };

// ---- setup: transposes (fp32) ----
__global__ void k_setup(const float* __restrict__ KN1, const float* __restrict__ KNc,
                        const float* __restrict__ K1,
                        float* __restrict__ KN1T, float* __restrict__ KNcT,
                        float* __restrict__ K1T) {
    for (int idx = threadIdx.x; idx < C * C; idx += blockDim.x) {
        int o = idx >> 6, i = idx & 63;
        KN1T[i * C + o] = KN1[o * C + i];   // [i][o] = KN1[o][i]
        KNcT[i * C + o] = KNc[o * C + i];   // [i][o] = KNclose[o][i]
    }
    for (int idx = threadIdx.x; idx < C * NIN; idx += blockDim.x) {
        int o = idx >> 4, i = idx & 15;
        K1T[i * C + o] = K1[o * NIN + i];   // [i][o] = K1[o][i]
    }
}

// ---- degree / counts ----
__global__ void k_zero_cnt(int* __restrict__ cnt, int* __restrict__ degj) {
    int n = blockIdx.x * blockDim.x + threadIdx.x;
    if (n < NN) { cnt[n] = 0; degj[n] = 1; }          // self loop in degree
}
__global__ void k_count(const int* __restrict__ iInd, const int* __restrict__ jInd,
                        int* __restrict__ cnt, int* __restrict__ degj) {
    int e = blockIdx.x * blockDim.x + threadIdx.x;
    if (e < NE) {
        int i = iInd[e], j = jInd[e];
        atomicAdd(&cnt[i], 1);
        atomicAdd(&cnt[j], 1);
        atomicAdd(&degj[j], 1);
    }
}
__global__ void k_dinv(const int* __restrict__ degj, float* __restrict__ dinv) {
    int n = blockIdx.x * blockDim.x + threadIdx.x;
    if (n < NN) dinv[n] = 1.0f / sqrtf((float)degj[n]);
}

// blocked single-block scan: 1024 threads x 49 nodes each
#define NPT 49
__global__ void k_scan(const int* __restrict__ cnt, int* __restrict__ rowptr,
                       int* __restrict__ cursor) {
    __shared__ int tmp[1024];
    int tid = threadIdx.x;
    int base = tid * NPT;
    int s = 0;
    for (int i = 0; i < NPT; i++) { int n = base + i; if (n < NN) s += cnt[n]; }
    tmp[tid] = s;
    __syncthreads();
    for (int off = 1; off < 1024; off <<= 1) {
        int a = (tid >= off) ? tmp[tid - off] : 0;
        __syncthreads();
        tmp[tid] += a;
        __syncthreads();
    }
    int excl = tmp[tid] - s;
    for (int i = 0; i < NPT; i++) {
        int n = base + i;
        if (n < NN) { rowptr[n] = excl; cursor[n] = excl; excl += cnt[n]; }
    }
    if (tid == 1023) rowptr[NN] = excl;   // base >= NN -> excl == grand total
}

// ---- fill: per-node cursor atomics, packed 4B adjacency (other:16 | f16(+-a):16) ----
__global__ void k_fill(const int* __restrict__ iInd, const int* __restrict__ jInd,
                       const float* __restrict__ dinv, int* __restrict__ cursor,
                       uint32_t* __restrict__ adjp) {
    int e = blockIdx.x * blockDim.x + threadIdx.x;
    if (e < NE) {
        int i = iInd[e], j = jInd[e];
        float a = dinv[i] * dinv[j];
        PK2 t; t.u = (unsigned)j; t.h[1] = (_Float16)a;     // target=i: other=j, +a
        int p = atomicAdd(&cursor[i], 1);
        adjp[p] = t.u;
        PK2 s; s.u = (unsigned)i; s.h[1] = (_Float16)(-a);  // target=j: other=i, -a
        p = atomicAdd(&cursor[j], 1);
        adjp[p] = s.u;
    }
}

// ---- opening: x = relu(K1*xn); u0 = KN1*x (f16) ----
__launch_bounds__(256)
__global__ void k_open_u(const float* __restrict__ xn, const float* __restrict__ K1T,
                         const float* __restrict__ KN1T,
                         float* __restrict__ x, _Float16* __restrict__ u0) {
    __shared__ float sK1T[NIN * C];
    __shared__ float sKT[C * C];
    for (int idx = threadIdx.x; idx < NIN * C; idx += 256) sK1T[idx] = K1T[idx];
    for (int idx = threadIdx.x; idx < C * C; idx += 256) sKT[idx] = KN1T[idx];
    __syncthreads();
    int wv = threadIdx.x >> 6, lane = threadIdx.x & 63;
    int n = blockIdx.x * 4 + wv;
    float acc = 0.f;
#pragma unroll
    for (int i = 0; i < NIN; i++)
        acc = fmaf(sK1T[i * C + lane], xn[i * NN + n], acc);
    float xr = fmaxf(acc, 0.f);
    x[n * C + lane] = xr;
    float ua = 0.f;
    for (int i = 0; i < C; i++)
        ua = fmaf(sKT[i * C + lane], __shfl(xr, i, 64), ua);
    u0[n * C + lane] = (_Float16)ua;
}

// ---- gather core over packed adjacency (computed per 32-lane group, channel pair cp) ----
#define GATHER_CORE(UP, ADJP, K0, K1E)                                        \
    float ax = 0.f, ay = 0.f;                                                 \
    int k = (K0);                                                             \
    for (; k + 8 <= (K1E); k += 8) {                                          \
        uint32_t p0 = (ADJP)[k + grp];                                        \
        uint32_t p1 = (ADJP)[k + 2 + grp];                                    \
        uint32_t p2 = (ADJP)[k + 4 + grp];                                    \
        uint32_t p3 = (ADJP)[k + 6 + grp];                                    \
        PK2 w0, w1, w2, w3; w0.u = p0; w1.u = p1; w2.u = p2; w3.u = p3;       \
        uint32_t q0 = (UP)[(size_t)(p0 & 0xFFFFu) * 32 + cp];                 \
        uint32_t q1 = (UP)[(size_t)(p1 & 0xFFFFu) * 32 + cp];                 \
        uint32_t q2 = (UP)[(size_t)(p2 & 0xFFFFu) * 32 + cp];                 \
        uint32_t q3 = (UP)[(size_t)(p3 & 0xFFFFu) * 32 + cp];                 \
        float a0 = (float)w0.h[1], a1 = (float)w1.h[1];                       \
        float a2 = (float)w2.h[1], a3 = (float)w3.h[1];                       \
        PK2 c0, c1, c2, c3; c0.u = q0; c1.u = q1; c2.u = q2; c3.u = q3;       \
        ax = fmaf(a0, fmaxf(a0 * (unx - (float)c0.h[0]), 0.f), ax);           \
        ay = fmaf(a0, fmaxf(a0 * (uny - (float)c0.h[1]), 0.f), ay);           \
        ax = fmaf(a1, fmaxf(a1 * (unx - (float)c1.h[0]), 0.f), ax);           \
        ay = fmaf(a1, fmaxf(a1 * (uny - (float)c1.h[1]), 0.f), ay);           \
        ax = fmaf(a2, fmaxf(a2 * (unx - (float)c2.h[0]), 0.f), ax);           \
        ay = fmaf(a2, fmaxf(a2 * (uny - (float)c2.h[1]), 0.f), ay);           \
        ax = fmaf(a3, fmaxf(a3 * (unx - (float)c3.h[0]), 0.f), ax);           \
        ay = fmaf(a3, fmaxf(a3 * (uny - (float)c3.h[1]), 0.f), ay);           \
    }                                                                         \
    for (; k + 2 <= (K1E); k += 2) {                                          \
        uint32_t p0 = (ADJP)[k + grp];                                        \
        PK2 w0; w0.u = p0;                                                    \
        uint32_t q0 = (UP)[(size_t)(p0 & 0xFFFFu) * 32 + cp];                 \
        float a0 = (float)w0.h[1];                                            \
        PK2 c0; c0.u = q0;                                                    \
        ax = fmaf(a0, fmaxf(a0 * (unx - (float)c0.h[0]), 0.f), ax);           \
        ay = fmaf(a0, fmaxf(a0 * (uny - (float)c0.h[1]), 0.f), ay);           \
    }                                                                         \
    if (k < (K1E) && grp == 0) {                                              \
        uint32_t p0 = (ADJP)[k];                                              \
        PK2 w0; w0.u = p0;                                                    \
        uint32_t q0 = (UP)[(size_t)(p0 & 0xFFFFu) * 32 + cp];                 \
        float a0 = (float)w0.h[1];                                            \
        PK2 c0; c0.u = q0;                                                    \
        ax = fmaf(a0, fmaxf(a0 * (unx - (float)c0.h[0]), 0.f), ax);           \
        ay = fmaf(a0, fmaxf(a0 * (uny - (float)c0.h[1]), 0.f), ay);           \
    }                                                                         \
    ax += __shfl_xor(ax, 32, 64);                                             \
    ay += __shfl_xor(ay, 32, 64);

// ---- per-layer fused kernel (layers 0..2):
//   s_n = sum_adj a*relu(a*(u_n - u_other));  x -= dtH*(KN1^T s);  unext = KN1*x
__launch_bounds__(256)
__global__ void k_glayer(const int* __restrict__ rowptr, const uint32_t* __restrict__ adjp,
                         const _Float16* __restrict__ ucur,
                         const float* __restrict__ KN1, const float* __restrict__ KN1T,
                         float* __restrict__ x, _Float16* __restrict__ unext) {
    __shared__ float sM[C * C];    // raw KN1 [i*C+o] -> d[o] = sum_i KN1[i,o] s[i]
    __shared__ float sKT[C * C];   // KN1T [i*C+o]   -> u[o] = sum_i KN1[o,i] x[i]
    for (int idx = threadIdx.x; idx < C * C; idx += 256) { sM[idx] = KN1[idx]; sKT[idx] = KN1T[idx]; }
    __syncthreads();
    int wv = threadIdx.x >> 6, lane = threadIdx.x & 63;
    int n = blockIdx.x * 4 + wv;
    const int grp = lane >> 5, cp = lane & 31;
    const uint32_t* up = (const uint32_t*)ucur;   // 32 f16x2 per node row
    PK2 pn; pn.u = up[n * 32 + cp];
    float unx = (float)pn.h[0], uny = (float)pn.h[1];
    GATHER_CORE(up, adjp, rowptr[n], rowptr[n + 1])
    float lowv = __shfl(ax, lane >> 1, 64);
    float highv = __shfl(ay, lane >> 1, 64);
    float sc = (lane & 1) ? highv : lowv;          // lane = channel now
    float dacc = 0.f;
    for (int i = 0; i < C; i++)
        dacc = fmaf(sM[i * C + lane], __shfl(sc, i, 64), dacc);
    float xnew = fmaf(-DTH, dacc, x[n * C + lane]);
    x[n * C + lane] = xnew;
    float ua = 0.f;
    for (int i = 0; i < C; i++)
        ua = fmaf(sKT[i * C + lane], __shfl(xnew, i, 64), ua);
    unext[n * C + lane] = (_Float16)ua;
}

// ---- final layer: same gather core, epilogue = KNclose + log_softmax ----
__launch_bounds__(256)
__global__ void k_gclose(const int* __restrict__ rowptr, const uint32_t* __restrict__ adjp,
                         const _Float16* __restrict__ ucur,
                         const float* __restrict__ KN1, const float* __restrict__ KNcT,
                         const float* __restrict__ x, float* __restrict__ out) {
    __shared__ float sM[C * C];    // raw KN1
    __shared__ float sKc[C * C];   // KNcT
    for (int idx = threadIdx.x; idx < C * C; idx += 256) { sM[idx] = KN1[idx]; sKc[idx] = KNcT[idx]; }
    __syncthreads();
    int wv = threadIdx.x >> 6, lane = threadIdx.x & 63;
    int n = blockIdx.x * 4 + wv;
    const int grp = lane >> 5, cp = lane & 31;
    const uint32_t* up = (const uint32_t*)ucur;
    PK2 pn; pn.u = up[n * 32 + cp];
    float unx = (float)pn.h[0], uny = (float)pn.h[1];
    GATHER_CORE(up, adjp, rowptr[n], rowptr[n + 1])
    float lowv = __shfl(ax, lane >> 1, 64);
    float highv = __shfl(ay, lane >> 1, 64);
    float sc = (lane & 1) ? highv : lowv;
    float dacc = 0.f;
    for (int i = 0; i < C; i++)
        dacc = fmaf(sM[i * C + lane], __shfl(sc, i, 64), dacc);
    float xnew = fmaf(-DTH, dacc, x[n * C + lane]);
    float o = 0.f;
    for (int i = 0; i < C; i++)
        o = fmaf(sKc[i * C + lane], __shfl(xnew, i, 64), o);
    float m = o;
#pragma unroll
    for (int off = 32; off; off >>= 1) m = fmaxf(m, __shfl_xor(m, off, 64));
    float sum = expf(o - m);
#pragma unroll
    for (int off = 32; off; off >>= 1) sum += __shfl_xor(sum, off, 64);
    out[n * C + lane] = o - m - logf(sum);
}

extern "C" void kernel_launch(void* const* d_in, const int* in_sizes, int n_in,
                              void* d_out, int out_size, void* d_ws, size_t ws_size,
                              hipStream_t stream) {
    (void)in_sizes; (void)n_in; (void)out_size; (void)ws_size;
    const float* xn   = (const float*)d_in[0];
    const int* iInd   = (const int*)d_in[1];
    const int* jInd   = (const int*)d_in[2];
    // d_in[3] = n_nodes scalar (fixed 50000)
    const float* K1   = (const float*)d_in[4];
    const float* KN1  = (const float*)d_in[5];
    const float* KNc  = (const float*)d_in[6];
    float* out = (float*)d_out;

    char* base = (char*)d_ws;
    size_t off = 0;
    auto alloc = [&](size_t bytes) { char* p = base + off; off = (off + bytes + 255) & ~(size_t)255; return p; };
    float* KN1T = (float*)alloc(C * C * 4);
    float* KNcT = (float*)alloc(C * C * 4);
    float* K1T  = (float*)alloc(NIN * C * 4);
    int* degj   = (int*)alloc(NN * 4);
    int* cnt    = (int*)alloc(NN * 4);
    int* rowptr = (int*)alloc((NN + 1) * 4);
    int* cursor = (int*)alloc(NN * 4);
    float* dinv = (float*)alloc(NN * 4);
    float* x    = (float*)alloc((size_t)NN * C * 4);       // 12.8 MB
    _Float16* ua = (_Float16*)alloc((size_t)NN * C * 2);   // 6.4 MB
    _Float16* ub = (_Float16*)alloc((size_t)NN * C * 2);   // 6.4 MB
    uint32_t* adjp = (uint32_t*)alloc((size_t)2 * NE * 4); // 12.8 MB

    // prolog: transposes, degrees, CSR adjacency (per-node cursor fill, packed 4B entries)
    k_setup<<<1, 256, 0, stream>>>(KN1, KNc, K1, KN1T, KNcT, K1T);
    k_zero_cnt<<<(NN + 255) / 256, 256, 0, stream>>>(cnt, degj);
    k_count<<<NE / 256, 256, 0, stream>>>(iInd, jInd, cnt, degj);
    k_dinv<<<(NN + 255) / 256, 256, 0, stream>>>(degj, dinv);
    k_scan<<<1, 1024, 0, stream>>>(cnt, rowptr, cursor);
    k_fill<<<NE / 256, 256, 0, stream>>>(iInd, jInd, dinv, cursor, adjp);

    // opening + u0
    k_open_u<<<NN / 4, 256, 0, stream>>>(xn, K1T, KN1T, x, ua);

    // 4 layers: fused gather + KN1^T + update + next-u (double-buffered u)
    k_glayer<<<NN / 4, 256, 0, stream>>>(rowptr, adjp, ua, KN1, KN1T, x, ub);
    k_glayer<<<NN / 4, 256, 0, stream>>>(rowptr, adjp, ub, KN1, KN1T, x, ua);
    k_glayer<<<NN / 4, 256, 0, stream>>>(rowptr, adjp, ua, KN1, KN1T, x, ub);
    k_gclose<<<NN / 4, 256, 0, stream>>>(rowptr, adjp, ub, KN1, KNcT, x, out);
}

// Round 8
// 1096.751 us; speedup vs baseline: 1.9316x; 1.2128x over previous
//
#include <hip/hip_runtime.h>

#define NN 50000
#define NE 1600000
#define C 64            // NOPEN == NUM_OUTPUT == 64
#define NIN 16
#define DTH 0.025f      // dt*H = (1.0/4)*0.1
#define PSZ 6250        // nodes per partition (8 * 6250 == 50000)
#define PB  128         // blocks per partition for count/fill

union PK2 { uint32_t u; _Float16 h[2]; };

// ---- setup: transposes (fp32) ----
__global__ void k_setup(const float* __restrict__ KN1, const float* __restrict__ KNc,
                        const float* __restrict__ K1,
                        float* __restrict__ KN1T, float* __restrict__ KNcT,
                        float* __restrict__ K1T) {
    for (int idx = threadIdx.x; idx < C * C; idx += blockDim.x) {
        int o = idx >> 6, i = idx & 63;
        KN1T[i * C + o] = KN1[o * C + i];   // [i][o] = KN1[o][i]
        KNcT[i * C + o] = KNc[o * C + i];   // [i][o] = KNclose[o][i]
    }
    for (int idx = threadIdx.x; idx < C * NIN; idx += blockDim.x) {
        int o = idx >> 4, i = idx & 15;
        K1T[i * C + o] = K1[o * NIN + i];   // [i][o] = K1[o][i]
    }
}

// ---- packed counts: low16 = incidence count, high16 = gcn degree (init 1 for self loop) ----
__global__ void k_init_pk(unsigned* __restrict__ pk) {
    int n = blockIdx.x * blockDim.x + threadIdx.x;
    if (n < NN) pk[n] = 0x10000u;
}
// XCD-partitioned count: blocks with blockIdx%8==p only touch nodes in partition p
__global__ void k_count2(const int* __restrict__ iInd, const int* __restrict__ jInd,
                         unsigned* __restrict__ pk) {
    int p = blockIdx.x & 7;
    int lo = p * PSZ, hi = lo + PSZ;
    int stride = (gridDim.x >> 3) * blockDim.x;
    for (int e = (blockIdx.x >> 3) * blockDim.x + threadIdx.x; e < NE; e += stride) {
        int i = iInd[e], j = jInd[e];
        if (i >= lo && i < hi) atomicAdd(&pk[i], 1u);
        if (j >= lo && j < hi) atomicAdd(&pk[j], 0x10001u);
    }
}
__global__ void k_dinv(const unsigned* __restrict__ pk, float* __restrict__ dinv) {
    int n = blockIdx.x * blockDim.x + threadIdx.x;
    if (n < NN) dinv[n] = 1.0f / sqrtf((float)(pk[n] >> 16));
}

// blocked single-block scan: 1024 threads x 49 nodes each
#define NPT 49
__global__ void k_scan(const unsigned* __restrict__ pk, int* __restrict__ rowptr,
                       int* __restrict__ cursor) {
    __shared__ int tmp[1024];
    int tid = threadIdx.x;
    int base = tid * NPT;
    int s = 0;
    for (int i = 0; i < NPT; i++) { int n = base + i; if (n < NN) s += (int)(pk[n] & 0xFFFFu); }
    tmp[tid] = s;
    __syncthreads();
    for (int off = 1; off < 1024; off <<= 1) {
        int a = (tid >= off) ? tmp[tid - off] : 0;
        __syncthreads();
        tmp[tid] += a;
        __syncthreads();
    }
    int excl = tmp[tid] - s;
    for (int i = 0; i < NPT; i++) {
        int n = base + i;
        if (n < NN) { rowptr[n] = excl; cursor[n] = excl; excl += (int)(pk[n] & 0xFFFFu); }
    }
    if (tid == 1023) rowptr[NN] = excl;
}

// ---- XCD-partitioned fill: partition p's adjacency region written only by blockIdx%8==p ----
__global__ void k_fill2(const int* __restrict__ iInd, const int* __restrict__ jInd,
                        const float* __restrict__ dinv, int* __restrict__ cursor,
                        uint32_t* __restrict__ adjp) {
    int p = blockIdx.x & 7;
    int lo = p * PSZ, hi = lo + PSZ;
    int stride = (gridDim.x >> 3) * blockDim.x;
    for (int e = (blockIdx.x >> 3) * blockDim.x + threadIdx.x; e < NE; e += stride) {
        int i = iInd[e], j = jInd[e];
        bool wi = (i >= lo && i < hi);
        bool wj = (j >= lo && j < hi);
        if (wi | wj) {
            float a = dinv[i] * dinv[j];
            if (wi) {
                PK2 t; t.u = (unsigned)j; t.h[1] = (_Float16)a;     // target=i: other=j, +a
                adjp[atomicAdd(&cursor[i], 1)] = t.u;
            }
            if (wj) {
                PK2 s; s.u = (unsigned)i; s.h[1] = (_Float16)(-a);  // target=j: other=i, -a
                adjp[atomicAdd(&cursor[j], 1)] = s.u;
            }
        }
    }
}

// ---- opening: x = relu(K1*xn); u0 = KN1*x (f16) ----
__launch_bounds__(256)
__global__ void k_open_u(const float* __restrict__ xn, const float* __restrict__ K1T,
                         const float* __restrict__ KN1T,
                         float* __restrict__ x, _Float16* __restrict__ u0) {
    __shared__ float sK1T[NIN * C];
    __shared__ float sKT[C * C];
    for (int idx = threadIdx.x; idx < NIN * C; idx += 256) sK1T[idx] = K1T[idx];
    for (int idx = threadIdx.x; idx < C * C; idx += 256) sKT[idx] = KN1T[idx];
    __syncthreads();
    int wv = threadIdx.x >> 6, lane = threadIdx.x & 63;
    int n = blockIdx.x * 4 + wv;
    float acc = 0.f;
#pragma unroll
    for (int i = 0; i < NIN; i++)
        acc = fmaf(sK1T[i * C + lane], xn[i * NN + n], acc);
    float xr = fmaxf(acc, 0.f);
    x[n * C + lane] = xr;
    float ua = 0.f;
    for (int i = 0; i < C; i++)
        ua = fmaf(sKT[i * C + lane], __shfl(xr, i, 64), ua);
    u0[n * C + lane] = (_Float16)ua;
}

// ---- gather primitives ----
__device__ __forceinline__ void edge_op(uint32_t w, const uint32_t* __restrict__ up, int cp,
                                        float unx, float uny, float& ax, float& ay) {
    PK2 wv; wv.u = w;
    uint32_t q = up[(size_t)(w & 0xFFFFu) * 32 + cp];
    float a = (float)wv.h[1];
    PK2 c; c.u = q;
    ax = fmaf(a, fmaxf(a * (unx - (float)c.h[0]), 0.f), ax);
    ay = fmaf(a, fmaxf(a * (uny - (float)c.h[1]), 0.f), ay);
}

// process `cnt` staged incidences held in areg (one entry per lane), split 2-per-iter across groups
__device__ __forceinline__ void gather_chunk(uint32_t areg, int cnt,
                                             const uint32_t* __restrict__ up, int cp, int grp,
                                             float unx, float uny, float& ax, float& ay) {
    int t = 0;
    for (; t + 16 <= cnt; t += 16) {
        uint32_t w0 = __shfl(areg, t + grp, 64);
        uint32_t w1 = __shfl(areg, t + 2 + grp, 64);
        uint32_t w2 = __shfl(areg, t + 4 + grp, 64);
        uint32_t w3 = __shfl(areg, t + 6 + grp, 64);
        uint32_t w4 = __shfl(areg, t + 8 + grp, 64);
        uint32_t w5 = __shfl(areg, t + 10 + grp, 64);
        uint32_t w6 = __shfl(areg, t + 12 + grp, 64);
        uint32_t w7 = __shfl(areg, t + 14 + grp, 64);
        uint32_t q0 = up[(size_t)(w0 & 0xFFFFu) * 32 + cp];
        uint32_t q1 = up[(size_t)(w1 & 0xFFFFu) * 32 + cp];
        uint32_t q2 = up[(size_t)(w2 & 0xFFFFu) * 32 + cp];
        uint32_t q3 = up[(size_t)(w3 & 0xFFFFu) * 32 + cp];
        uint32_t q4 = up[(size_t)(w4 & 0xFFFFu) * 32 + cp];
        uint32_t q5 = up[(size_t)(w5 & 0xFFFFu) * 32 + cp];
        uint32_t q6 = up[(size_t)(w6 & 0xFFFFu) * 32 + cp];
        uint32_t q7 = up[(size_t)(w7 & 0xFFFFu) * 32 + cp];
        PK2 W, Q;
#define ACC1(WW, QQ) { W.u = (WW); Q.u = (QQ); float a_ = (float)W.h[1];                     \
        ax = fmaf(a_, fmaxf(a_ * (unx - (float)Q.h[0]), 0.f), ax);                           \
        ay = fmaf(a_, fmaxf(a_ * (uny - (float)Q.h[1]), 0.f), ay); }
        ACC1(w0, q0) ACC1(w1, q1) ACC1(w2, q2) ACC1(w3, q3)
        ACC1(w4, q4) ACC1(w5, q5) ACC1(w6, q6) ACC1(w7, q7)
#undef ACC1
    }
    for (; t + 2 <= cnt; t += 2) {
        uint32_t w = __shfl(areg, t + grp, 64);
        edge_op(w, up, cp, unx, uny, ax, ay);
    }
    if (t < cnt) {
        uint32_t w = __shfl(areg, t, 64);
        if (grp == 0) edge_op(w, up, cp, unx, uny, ax, ay);
    }
}

__device__ __forceinline__ void gather_node(int n, const int* __restrict__ rowptr,
                                            const uint32_t* __restrict__ adjp,
                                            const uint32_t* __restrict__ up,
                                            int lane, int grp, int cp,
                                            float unx, float uny, float& ax, float& ay) {
    int k0 = rowptr[n], k1 = rowptr[n + 1];
    int deg = k1 - k0;
    // register-stage up to 128 adjacency entries with 2 coalesced loads
    uint32_t a0r = (lane < deg) ? adjp[k0 + lane] : 0u;
    uint32_t a1r = (64 + lane < deg) ? adjp[k0 + 64 + lane] : 0u;
    gather_chunk(a0r, deg < 64 ? deg : 64, up, cp, grp, unx, uny, ax, ay);
    if (deg > 64)
        gather_chunk(a1r, (deg - 64) < 64 ? (deg - 64) : 64, up, cp, grp, unx, uny, ax, ay);
    if (deg > 128) {          // rare tail (deg > 128): direct loads
        int k = k0 + 128;
        for (; k + 2 <= k1; k += 2)
            edge_op(adjp[k + grp], up, cp, unx, uny, ax, ay);
        if (k < k1 && grp == 0)
            edge_op(adjp[k], up, cp, unx, uny, ax, ay);
    }
    ax += __shfl_xor(ax, 32, 64);
    ay += __shfl_xor(ay, 32, 64);
}

// ---- per-layer fused kernel (layers 0..2):
//   s_n = sum_adj a*relu(a*(u_n - u_other));  x -= dtH*(KN1^T s);  unext = KN1*x
__launch_bounds__(256)
__global__ void k_glayer(const int* __restrict__ rowptr, const uint32_t* __restrict__ adjp,
                         const _Float16* __restrict__ ucur,
                         const float* __restrict__ KN1, const float* __restrict__ KN1T,
                         float* __restrict__ x, _Float16* __restrict__ unext) {
    __shared__ float sM[C * C];    // raw KN1 [i*C+o] -> d[o] = sum_i KN1[i,o] s[i]
    __shared__ float sKT[C * C];   // KN1T [i*C+o]   -> u[o] = sum_i KN1[o,i] x[i]
    for (int idx = threadIdx.x; idx < C * C; idx += 256) { sM[idx] = KN1[idx]; sKT[idx] = KN1T[idx]; }
    __syncthreads();
    int wv = threadIdx.x >> 6, lane = threadIdx.x & 63;
    int n = blockIdx.x * 4 + wv;
    const int grp = lane >> 5, cp = lane & 31;
    const uint32_t* up = (const uint32_t*)ucur;   // 32 f16x2 per node row
    PK2 pn; pn.u = up[n * 32 + cp];
    float unx = (float)pn.h[0], uny = (float)pn.h[1];
    float ax = 0.f, ay = 0.f;
    gather_node(n, rowptr, adjp, up, lane, grp, cp, unx, uny, ax, ay);
    float lowv = __shfl(ax, lane >> 1, 64);
    float highv = __shfl(ay, lane >> 1, 64);
    float sc = (lane & 1) ? highv : lowv;          // lane = channel now
    float dacc = 0.f;
    for (int i = 0; i < C; i++)
        dacc = fmaf(sM[i * C + lane], __shfl(sc, i, 64), dacc);
    float xnew = fmaf(-DTH, dacc, x[n * C + lane]);
    x[n * C + lane] = xnew;
    float ua = 0.f;
    for (int i = 0; i < C; i++)
        ua = fmaf(sKT[i * C + lane], __shfl(xnew, i, 64), ua);
    unext[n * C + lane] = (_Float16)ua;
}

// ---- final layer: same gather core, epilogue = KNclose + log_softmax ----
__launch_bounds__(256)
__global__ void k_gclose(const int* __restrict__ rowptr, const uint32_t* __restrict__ adjp,
                         const _Float16* __restrict__ ucur,
                         const float* __restrict__ KN1, const float* __restrict__ KNcT,
                         const float* __restrict__ x, float* __restrict__ out) {
    __shared__ float sM[C * C];    // raw KN1
    __shared__ float sKc[C * C];   // KNcT
    for (int idx = threadIdx.x; idx < C * C; idx += 256) { sM[idx] = KN1[idx]; sKc[idx] = KNcT[idx]; }
    __syncthreads();
    int wv = threadIdx.x >> 6, lane = threadIdx.x & 63;
    int n = blockIdx.x * 4 + wv;
    const int grp = lane >> 5, cp = lane & 31;
    const uint32_t* up = (const uint32_t*)ucur;
    PK2 pn; pn.u = up[n * 32 + cp];
    float unx = (float)pn.h[0], uny = (float)pn.h[1];
    float ax = 0.f, ay = 0.f;
    gather_node(n, rowptr, adjp, up, lane, grp, cp, unx, uny, ax, ay);
    float lowv = __shfl(ax, lane >> 1, 64);
    float highv = __shfl(ay, lane >> 1, 64);
    float sc = (lane & 1) ? highv : lowv;
    float dacc = 0.f;
    for (int i = 0; i < C; i++)
        dacc = fmaf(sM[i * C + lane], __shfl(sc, i, 64), dacc);
    float xnew = fmaf(-DTH, dacc, x[n * C + lane]);
    float o = 0.f;
    for (int i = 0; i < C; i++)
        o = fmaf(sKc[i * C + lane], __shfl(xnew, i, 64), o);
    float m = o;
#pragma unroll
    for (int off = 32; off; off >>= 1) m = fmaxf(m, __shfl_xor(m, off, 64));
    float sum = expf(o - m);
#pragma unroll
    for (int off = 32; off; off >>= 1) sum += __shfl_xor(sum, off, 64);
    out[n * C + lane] = o - m - logf(sum);
}

extern "C" void kernel_launch(void* const* d_in, const int* in_sizes, int n_in,
                              void* d_out, int out_size, void* d_ws, size_t ws_size,
                              hipStream_t stream) {
    (void)in_sizes; (void)n_in; (void)out_size; (void)ws_size;
    const float* xn   = (const float*)d_in[0];
    const int* iInd   = (const int*)d_in[1];
    const int* jInd   = (const int*)d_in[2];
    // d_in[3] = n_nodes scalar (fixed 50000)
    const float* K1   = (const float*)d_in[4];
    const float* KN1  = (const float*)d_in[5];
    const float* KNc  = (const float*)d_in[6];
    float* out = (float*)d_out;

    char* base = (char*)d_ws;
    size_t off = 0;
    auto alloc = [&](size_t bytes) { char* p = base + off; off = (off + bytes + 255) & ~(size_t)255; return p; };
    float* KN1T = (float*)alloc(C * C * 4);
    float* KNcT = (float*)alloc(C * C * 4);
    float* K1T  = (float*)alloc(NIN * C * 4);
    unsigned* pk = (unsigned*)alloc(NN * 4);
    int* rowptr = (int*)alloc((NN + 1) * 4);
    int* cursor = (int*)alloc(NN * 4);
    float* dinv = (float*)alloc(NN * 4);
    float* x    = (float*)alloc((size_t)NN * C * 4);       // 12.8 MB
    _Float16* ua = (_Float16*)alloc((size_t)NN * C * 2);   // 6.4 MB
    _Float16* ub = (_Float16*)alloc((size_t)NN * C * 2);   // 6.4 MB
    uint32_t* adjp = (uint32_t*)alloc((size_t)2 * NE * 4); // 12.8 MB

    // prolog: transposes, degrees, CSR adjacency (XCD-partitioned count + fill)
    k_setup<<<1, 256, 0, stream>>>(KN1, KNc, K1, KN1T, KNcT, K1T);
    k_init_pk<<<(NN + 255) / 256, 256, 0, stream>>>(pk);
    k_count2<<<8 * PB, 256, 0, stream>>>(iInd, jInd, pk);
    k_dinv<<<(NN + 255) / 256, 256, 0, stream>>>(pk, dinv);
    k_scan<<<1, 1024, 0, stream>>>(pk, rowptr, cursor);
    k_fill2<<<8 * PB, 256, 0, stream>>>(iInd, jInd, dinv, cursor, adjp);

    // opening + u0
    k_open_u<<<NN / 4, 256, 0, stream>>>(xn, K1T, KN1T, x, ua);

    // 4 layers: fused gather + KN1^T + update + next-u (double-buffered u)
    k_glayer<<<NN / 4, 256, 0, stream>>>(rowptr, adjp, ua, KN1, KN1T, x, ub);
    k_glayer<<<NN / 4, 256, 0, stream>>>(rowptr, adjp, ub, KN1, KN1T, x, ua);
    k_glayer<<<NN / 4, 256, 0, stream>>>(rowptr, adjp, ua, KN1, KN1T, x, ub);
    k_gclose<<<NN / 4, 256, 0, stream>>>(rowptr, adjp, ub, KN1, KNcT, x, out);
}

// Round 9
// 1060.824 us; speedup vs baseline: 1.9970x; 1.0339x over previous
//
#include <hip/hip_runtime.h>

#define NN 50000
#define NE 1600000
#define C 64            // NOPEN == NUM_OUTPUT == 64
#define NIN 16
#define DTH 0.025f      // dt*H = (1.0/4)*0.1
#define ASC 16.0f       // adjacency weight scale -> s scaled by 256
#define SDIV 256.0f
#define PSZ 6250        // nodes per partition (8 * 6250 == 50000)
#define PB  128         // blocks per partition for fill
#define NPW 16          // nodes per wave in layer kernels

typedef _Float16 f16x2 __attribute__((ext_vector_type(2)));
union U32H2 { uint32_t u; f16x2 h; };
static __device__ __forceinline__ f16x2 u2h(uint32_t v) { U32H2 t; t.u = v; return t.h; }
static __device__ __forceinline__ uint32_t h2u(f16x2 v) { U32H2 t; t.h = v; return t.u; }

// ---- setup: KN1T (for open), KNcT (for close), M2 = KN1*KN1^T ----
__global__ void k_setup(const float* __restrict__ KN1, const float* __restrict__ KNc,
                        const float* __restrict__ K1,
                        float* __restrict__ KN1T, float* __restrict__ KNcT,
                        float* __restrict__ K1T, float* __restrict__ M2s) {
    for (int idx = threadIdx.x; idx < C * C; idx += blockDim.x) {
        int o = idx >> 6, i = idx & 63;
        KN1T[i * C + o] = KN1[o * C + i];   // [i][o] = KN1[o][i]
        KNcT[i * C + o] = KNc[o * C + i];   // [i][o] = KNclose[o][i]
    }
    for (int idx = threadIdx.x; idx < C * NIN; idx += blockDim.x) {
        int o = idx >> 4, i = idx & 15;
        K1T[i * C + o] = K1[o * NIN + i];
    }
    // M2s[p*64+o] = sum_i KN1[o,i]*KN1[p,i]
    for (int idx = threadIdx.x; idx < C * C; idx += blockDim.x) {
        int p = idx >> 6, o = idx & 63;
        float s = 0.f;
        for (int i = 0; i < C; i++)
            s = fmaf(KN1[o * C + i], KN1[p * C + i], s);
        M2s[idx] = s;
    }
}

// ---- packed counts: low16 = incidence count, high16 = gcn degree (init 1 self loop) ----
__global__ void k_init_pk(unsigned* __restrict__ pk) {
    int n = blockIdx.x * blockDim.x + threadIdx.x;
    if (n < NN) pk[n] = 0x10000u;
}
// single-pass count (counter array is tiny/L2-resident; partitioning not needed)
__global__ void k_count(const int* __restrict__ iInd, const int* __restrict__ jInd,
                        unsigned* __restrict__ pk) {
    int e = blockIdx.x * blockDim.x + threadIdx.x;
    if (e < NE) {
        atomicAdd(&pk[iInd[e]], 1u);
        atomicAdd(&pk[jInd[e]], 0x10001u);
    }
}
__global__ void k_dinv(const unsigned* __restrict__ pk, float* __restrict__ dinv) {
    int n = blockIdx.x * blockDim.x + threadIdx.x;
    if (n < NN) dinv[n] = 1.0f / sqrtf((float)(pk[n] >> 16));
}

// blocked single-block scan: 1024 threads x 49 nodes each
#define NPT 49
__global__ void k_scan(const unsigned* __restrict__ pk, int* __restrict__ rowptr,
                       int* __restrict__ cursor) {
    __shared__ int tmp[1024];
    int tid = threadIdx.x;
    int base = tid * NPT;
    int s = 0;
    for (int i = 0; i < NPT; i++) { int n = base + i; if (n < NN) s += (int)(pk[n] & 0xFFFFu); }
    tmp[tid] = s;
    __syncthreads();
    for (int off = 1; off < 1024; off <<= 1) {
        int a = (tid >= off) ? tmp[tid - off] : 0;
        __syncthreads();
        tmp[tid] += a;
        __syncthreads();
    }
    int excl = tmp[tid] - s;
    for (int i = 0; i < NPT; i++) {
        int n = base + i;
        if (n < NN) { rowptr[n] = excl; cursor[n] = excl; excl += (int)(pk[n] & 0xFFFFu); }
    }
    if (tid == 1023) rowptr[NN] = excl;
}

// ---- XCD-partitioned fill: packed entry = other:16 | f16(+-16a):16 ----
__global__ void k_fill2(const int* __restrict__ iInd, const int* __restrict__ jInd,
                        const float* __restrict__ dinv, int* __restrict__ cursor,
                        uint32_t* __restrict__ adjp) {
    int p = blockIdx.x & 7;
    int lo = p * PSZ, hi = lo + PSZ;
    int stride = (gridDim.x >> 3) * blockDim.x;
    for (int e = (blockIdx.x >> 3) * blockDim.x + threadIdx.x; e < NE; e += stride) {
        int i = iInd[e], j = jInd[e];
        bool wi = (i >= lo && i < hi);
        bool wj = (j >= lo && j < hi);
        if (wi | wj) {
            float a = ASC * dinv[i] * dinv[j];
            if (wi) {
                U32H2 t; t.u = (unsigned)j; t.h.y = (_Float16)a;     // target=i: other=j, +a
                adjp[atomicAdd(&cursor[i], 1)] = t.u;
            }
            if (wj) {
                U32H2 s2; s2.u = (unsigned)i; s2.h.y = (_Float16)(-a); // target=j: other=i, -a
                adjp[atomicAdd(&cursor[j], 1)] = s2.u;
            }
        }
    }
}

// ---- opening: x = relu(K1*xn); u0 = KN1*x (f16); sacc = 0 ----
__launch_bounds__(256)
__global__ void k_open_u(const float* __restrict__ xn, const float* __restrict__ K1T,
                         const float* __restrict__ KN1T,
                         float* __restrict__ x, _Float16* __restrict__ u0,
                         float* __restrict__ sacc) {
    __shared__ float sK1T[NIN * C];
    __shared__ float sKT[C * C];
    for (int idx = threadIdx.x; idx < NIN * C; idx += 256) sK1T[idx] = K1T[idx];
    for (int idx = threadIdx.x; idx < C * C; idx += 256) sKT[idx] = KN1T[idx];
    __syncthreads();
    int wv = threadIdx.x >> 6, lane = threadIdx.x & 63;
    int n = blockIdx.x * 4 + wv;
    float acc = 0.f;
#pragma unroll
    for (int i = 0; i < NIN; i++)
        acc = fmaf(sK1T[i * C + lane], xn[i * NN + n], acc);
    float xr = fmaxf(acc, 0.f);
    x[n * C + lane] = xr;
    sacc[n * C + lane] = 0.f;
    float ua = 0.f;
    for (int i = 0; i < C; i++)
        ua = fmaf(sKT[i * C + lane], __shfl(xr, i, 64), ua);
    u0[n * C + lane] = (_Float16)ua;
}

// ---- packed gather: per incidence, 16 lanes x f16x4; math in v_pk_* f16 ----
#define PROCW(WV) {                                                           \
    uint32_t w_ = (WV);                                                       \
    uint2 q_ = upv[(w_ & 0xFFFFu) * 16 + li];                                 \
    U32H2 aw_; aw_.u = w_;                                                    \
    f16x2 a2_ = { aw_.h.y, aw_.h.y };                                         \
    f16x2 d0_ = un01 - u2h(q_.x);                                             \
    f16x2 d1_ = un23 - u2h(q_.y);                                             \
    f16x2 r0_ = __builtin_elementwise_max(a2_ * d0_, zz);                     \
    f16x2 r1_ = __builtin_elementwise_max(a2_ * d1_, zz);                     \
    acc01 = a2_ * r0_ + acc01;                                                \
    acc23 = a2_ * r1_ + acc23;                                                \
}
#define PROC(REG, TT) PROCW((uint32_t)__shfl((int)(REG), (TT) + g, 64))

// computes s_lane (scaled s for channel = lane) for node n
#define GATHER_S(N)                                                           \
    uint2 unq = upv[(N) * 16 + li];                                           \
    f16x2 un01 = u2h(unq.x), un23 = u2h(unq.y);                               \
    int k0 = rowptr[N], k1 = rowptr[(N) + 1];                                 \
    int deg = k1 - k0;                                                        \
    uint32_t a0r = (lane < deg) ? adjp[k0 + lane] : 0u;                       \
    uint32_t a1r = (64 + lane < deg) ? adjp[k0 + 64 + lane] : 0u;             \
    f16x2 zz = { (_Float16)0.f, (_Float16)0.f };                              \
    f16x2 acc01 = zz, acc23 = zz;                                             \
    int c1 = deg < 64 ? deg : 64;                                             \
    for (int t = 0; t < c1; t += 8) { PROC(a0r, t) PROC(a0r, t + 4) }         \
    if (deg > 64) {                                                           \
        int c2 = deg - 64; if (c2 > 64) c2 = 64;                              \
        for (int t = 0; t < c2; t += 8) { PROC(a1r, t) PROC(a1r, t + 4) }     \
    }                                                                         \
    if (deg > 128) {                                                          \
        for (int k = k0 + 128; k < k1; k += 4) {                              \
            uint32_t wt = (k + g < k1) ? adjp[k + g] : 0u;                    \
            PROCW(wt)                                                         \
        }                                                                     \
    }                                                                         \
    acc01 = acc01 + u2h((uint32_t)__shfl_xor((int)h2u(acc01), 16, 64));       \
    acc01 = acc01 + u2h((uint32_t)__shfl_xor((int)h2u(acc01), 32, 64));       \
    acc23 = acc23 + u2h((uint32_t)__shfl_xor((int)h2u(acc23), 16, 64));       \
    acc23 = acc23 + u2h((uint32_t)__shfl_xor((int)h2u(acc23), 32, 64));       \
    uint32_t r01 = (uint32_t)__shfl((int)h2u(acc01), lane >> 2, 64);          \
    uint32_t r23 = (uint32_t)__shfl((int)h2u(acc23), lane >> 2, 64);          \
    U32H2 selp; selp.u = (lane & 2) ? r23 : r01;                              \
    float s_lane = (float)((lane & 1) ? selp.h.y : selp.h.x);

// ---- layers 0..2: s = gather; unext = ucur - dtH*M2*s; sacc += s ----
__launch_bounds__(256)
__global__ void k_glayer(const int* __restrict__ rowptr, const uint32_t* __restrict__ adjp,
                         const _Float16* __restrict__ ucur, const float* __restrict__ M2s,
                         float* __restrict__ sacc, _Float16* __restrict__ unext) {
    int wv = threadIdx.x >> 6, lane = threadIdx.x & 63;
    int g = lane >> 4, li = lane & 15;
    float m2c[64];
#pragma unroll
    for (int p = 0; p < 64; p++) m2c[p] = M2s[p * C + lane];
    const uint2* upv = (const uint2*)ucur;
    int n0 = (blockIdx.x * 4 + wv) * NPW;
    int nend = n0 + NPW; if (nend > NN) nend = NN;
    for (int n = n0; n < nend; n++) {
        GATHER_S(n)
        float du = 0.f;
#pragma unroll
        for (int p = 0; p < 64; p++)
            du = fmaf(m2c[p], __shfl(s_lane, p, 64), du);
        float unew = (float)ucur[(size_t)n * C + lane] - (DTH / SDIV) * du;
        unext[(size_t)n * C + lane] = (_Float16)unew;
        sacc[(size_t)n * C + lane] += s_lane;
    }
}

// ---- final layer: stot = sacc + s; xf = x0 - dtH*KN1^T*stot; close + log_softmax ----
__launch_bounds__(256)
__global__ void k_gclose(const int* __restrict__ rowptr, const uint32_t* __restrict__ adjp,
                         const _Float16* __restrict__ ucur, const float* __restrict__ KN1,
                         const float* __restrict__ KNcT, const float* __restrict__ sacc,
                         const float* __restrict__ x, float* __restrict__ out) {
    __shared__ float sM[C * C];    // raw KN1: d[o] = sum_p KN1[p,o]*stot[p]
    __shared__ float sKc[C * C];   // KNcT
    for (int idx = threadIdx.x; idx < C * C; idx += 256) { sM[idx] = KN1[idx]; sKc[idx] = KNcT[idx]; }
    __syncthreads();
    int wv = threadIdx.x >> 6, lane = threadIdx.x & 63;
    int g = lane >> 4, li = lane & 15;
    const uint2* upv = (const uint2*)ucur;
    int n0 = (blockIdx.x * 4 + wv) * NPW;
    int nend = n0 + NPW; if (nend > NN) nend = NN;
    for (int n = n0; n < nend; n++) {
        GATHER_S(n)
        float stot = s_lane + sacc[(size_t)n * C + lane];
        float dx = 0.f;
#pragma unroll
        for (int p = 0; p < 64; p++)
            dx = fmaf(sM[p * C + lane], __shfl(stot, p, 64), dx);
        float xf = x[(size_t)n * C + lane] - (DTH / SDIV) * dx;
        float o = 0.f;
#pragma unroll
        for (int i = 0; i < 64; i++)
            o = fmaf(sKc[i * C + lane], __shfl(xf, i, 64), o);
        float m = o;
#pragma unroll
        for (int off2 = 32; off2; off2 >>= 1) m = fmaxf(m, __shfl_xor(m, off2, 64));
        float sum = expf(o - m);
#pragma unroll
        for (int off2 = 32; off2; off2 >>= 1) sum += __shfl_xor(sum, off2, 64);
        out[(size_t)n * C + lane] = o - m - logf(sum);
    }
}

extern "C" void kernel_launch(void* const* d_in, const int* in_sizes, int n_in,
                              void* d_out, int out_size, void* d_ws, size_t ws_size,
                              hipStream_t stream) {
    (void)in_sizes; (void)n_in; (void)out_size; (void)ws_size;
    const float* xn   = (const float*)d_in[0];
    const int* iInd   = (const int*)d_in[1];
    const int* jInd   = (const int*)d_in[2];
    // d_in[3] = n_nodes scalar (fixed 50000)
    const float* K1   = (const float*)d_in[4];
    const float* KN1  = (const float*)d_in[5];
    const float* KNc  = (const float*)d_in[6];
    float* out = (float*)d_out;

    char* base = (char*)d_ws;
    size_t off = 0;
    auto alloc = [&](size_t bytes) { char* p = base + off; off = (off + bytes + 255) & ~(size_t)255; return p; };
    float* KN1T = (float*)alloc(C * C * 4);
    float* KNcT = (float*)alloc(C * C * 4);
    float* K1T  = (float*)alloc(NIN * C * 4);
    float* M2s  = (float*)alloc(C * C * 4);
    unsigned* pk = (unsigned*)alloc(NN * 4);
    int* rowptr = (int*)alloc((NN + 1) * 4);
    int* cursor = (int*)alloc(NN * 4);
    float* dinv = (float*)alloc(NN * 4);
    float* x    = (float*)alloc((size_t)NN * C * 4);       // 12.8 MB
    float* sacc = (float*)alloc((size_t)NN * C * 4);       // 12.8 MB
    _Float16* ua = (_Float16*)alloc((size_t)NN * C * 2);   // 6.4 MB
    _Float16* ub = (_Float16*)alloc((size_t)NN * C * 2);   // 6.4 MB
    uint32_t* adjp = (uint32_t*)alloc((size_t)2 * NE * 4); // 12.8 MB

    // prolog
    k_setup<<<1, 256, 0, stream>>>(KN1, KNc, K1, KN1T, KNcT, K1T, M2s);
    k_init_pk<<<(NN + 255) / 256, 256, 0, stream>>>(pk);
    k_count<<<NE / 256, 256, 0, stream>>>(iInd, jInd, pk);
    k_dinv<<<(NN + 255) / 256, 256, 0, stream>>>(pk, dinv);
    k_scan<<<1, 1024, 0, stream>>>(pk, rowptr, cursor);
    k_fill2<<<8 * PB, 256, 0, stream>>>(iInd, jInd, dinv, cursor, adjp);

    // opening + u0 + sacc=0
    k_open_u<<<NN / 4, 256, 0, stream>>>(xn, K1T, KN1T, x, ua, sacc);

    // layers (each wave handles 16 nodes); 782 blocks cover 50048 node slots
    const int LB = (NN + 4 * NPW - 1) / (4 * NPW);
    k_glayer<<<LB, 256, 0, stream>>>(rowptr, adjp, ua, M2s, sacc, ub);
    k_glayer<<<LB, 256, 0, stream>>>(rowptr, adjp, ub, M2s, sacc, ua);
    k_glayer<<<LB, 256, 0, stream>>>(rowptr, adjp, ua, M2s, sacc, ub);
    k_gclose<<<LB, 256, 0, stream>>>(rowptr, adjp, ub, KN1, KNcT, sacc, x, out);
}

// Round 10
// 976.126 us; speedup vs baseline: 2.1703x; 1.0868x over previous
//
#include <hip/hip_runtime.h>

#define NN 50000
#define NE 1600000
#define C 64            // NOPEN == NUM_OUTPUT == 64
#define NIN 16
#define DTH 0.025f      // dt*H = (1.0/4)*0.1
#define ASC 16.0f       // adjacency weight scale -> s scaled by 256
#define SDIV 256.0f
#define PSZ 6250        // nodes per partition (8 * 6250 == 50000)
#define PB  128         // blocks per partition for fill

typedef _Float16 f16x2 __attribute__((ext_vector_type(2)));
union U32H2 { uint32_t u; f16x2 h; };
static __device__ __forceinline__ f16x2 u2h(uint32_t v) { U32H2 t; t.u = v; return t.h; }
static __device__ __forceinline__ uint32_t h2u(f16x2 v) { U32H2 t; t.h = v; return t.u; }

// ---- setup: KN1T (open), KNcT (close), M2 = KN1*KN1^T ----
__global__ void k_setup(const float* __restrict__ KN1, const float* __restrict__ KNc,
                        const float* __restrict__ K1,
                        float* __restrict__ KN1T, float* __restrict__ KNcT,
                        float* __restrict__ K1T, float* __restrict__ M2s) {
    for (int idx = threadIdx.x; idx < C * C; idx += blockDim.x) {
        int o = idx >> 6, i = idx & 63;
        KN1T[i * C + o] = KN1[o * C + i];
        KNcT[i * C + o] = KNc[o * C + i];
    }
    for (int idx = threadIdx.x; idx < C * NIN; idx += blockDim.x) {
        int o = idx >> 4, i = idx & 15;
        K1T[i * C + o] = K1[o * NIN + i];
    }
    // M2s[p*64+o] = sum_i KN1[o,i]*KN1[p,i]
    for (int idx = threadIdx.x; idx < C * C; idx += blockDim.x) {
        int p = idx >> 6, o = idx & 63;
        float s = 0.f;
        for (int i = 0; i < C; i++)
            s = fmaf(KN1[o * C + i], KN1[p * C + i], s);
        M2s[idx] = s;
    }
}

// ---- packed counts: low16 = incidence count, high16 = gcn degree ----
__global__ void k_init_pk(unsigned* __restrict__ pk) {
    int n = blockIdx.x * blockDim.x + threadIdx.x;
    if (n < NN) pk[n] = 0x10000u;
}
__global__ void k_count(const int* __restrict__ iInd, const int* __restrict__ jInd,
                        unsigned* __restrict__ pk) {
    int e = blockIdx.x * blockDim.x + threadIdx.x;
    if (e < NE) {
        atomicAdd(&pk[iInd[e]], 1u);
        atomicAdd(&pk[jInd[e]], 0x10001u);
    }
}
__global__ void k_dinv(const unsigned* __restrict__ pk, float* __restrict__ dinv) {
    int n = blockIdx.x * blockDim.x + threadIdx.x;
    if (n < NN) dinv[n] = 1.0f / sqrtf((float)(pk[n] >> 16));
}

// blocked single-block scan
#define NPT 49
__global__ void k_scan(const unsigned* __restrict__ pk, int* __restrict__ rowptr,
                       int* __restrict__ cursor) {
    __shared__ int tmp[1024];
    int tid = threadIdx.x;
    int base = tid * NPT;
    int s = 0;
    for (int i = 0; i < NPT; i++) { int n = base + i; if (n < NN) s += (int)(pk[n] & 0xFFFFu); }
    tmp[tid] = s;
    __syncthreads();
    for (int off = 1; off < 1024; off <<= 1) {
        int a = (tid >= off) ? tmp[tid - off] : 0;
        __syncthreads();
        tmp[tid] += a;
        __syncthreads();
    }
    int excl = tmp[tid] - s;
    for (int i = 0; i < NPT; i++) {
        int n = base + i;
        if (n < NN) { rowptr[n] = excl; cursor[n] = excl; excl += (int)(pk[n] & 0xFFFFu); }
    }
    if (tid == 1023) rowptr[NN] = excl;
}

// ---- XCD-partitioned fill: packed entry = other:16 | f16(+-16a):16 ----
__global__ void k_fill2(const int* __restrict__ iInd, const int* __restrict__ jInd,
                        const float* __restrict__ dinv, int* __restrict__ cursor,
                        uint32_t* __restrict__ adjp) {
    int p = blockIdx.x & 7;
    int lo = p * PSZ, hi = lo + PSZ;
    int stride = (gridDim.x >> 3) * blockDim.x;
    for (int e = (blockIdx.x >> 3) * blockDim.x + threadIdx.x; e < NE; e += stride) {
        int i = iInd[e], j = jInd[e];
        bool wi = (i >= lo && i < hi);
        bool wj = (j >= lo && j < hi);
        if (wi | wj) {
            float a = ASC * dinv[i] * dinv[j];
            if (wi) {
                U32H2 t; t.u = (unsigned)j; t.h.y = (_Float16)a;
                adjp[atomicAdd(&cursor[i], 1)] = t.u;
            }
            if (wj) {
                U32H2 s2; s2.u = (unsigned)i; s2.h.y = (_Float16)(-a);
                adjp[atomicAdd(&cursor[j], 1)] = s2.u;
            }
        }
    }
}

// ---- opening: x = relu(K1*xn); u0 = KN1*x (f16) ----
__launch_bounds__(256)
__global__ void k_open_u(const float* __restrict__ xn, const float* __restrict__ K1T,
                         const float* __restrict__ KN1T,
                         float* __restrict__ x, _Float16* __restrict__ u0) {
    __shared__ float sK1T[NIN * C];
    __shared__ float sKT[C * C];
    for (int idx = threadIdx.x; idx < NIN * C; idx += 256) sK1T[idx] = K1T[idx];
    for (int idx = threadIdx.x; idx < C * C; idx += 256) sKT[idx] = KN1T[idx];
    __syncthreads();
    int wv = threadIdx.x >> 6, lane = threadIdx.x & 63;
    int n = blockIdx.x * 4 + wv;
    float acc = 0.f;
#pragma unroll
    for (int i = 0; i < NIN; i++)
        acc = fmaf(sK1T[i * C + lane], xn[i * NN + n], acc);
    float xr = fmaxf(acc, 0.f);
    x[n * C + lane] = xr;
    float ua = 0.f;
    for (int i = 0; i < C; i++)
        ua = fmaf(sKT[i * C + lane], __shfl(xr, i, 64), ua);
    u0[n * C + lane] = (_Float16)ua;
}

// ---- packed gather: 16 lanes x f16x4 per incidence, 4 incidences per PROC (one/group) ----
#define PROCW(WV) {                                                           \
    uint32_t w_ = (WV);                                                       \
    uint2 q_ = upv[(w_ & 0xFFFFu) * 16 + li];                                 \
    U32H2 aw_; aw_.u = w_;                                                    \
    f16x2 a2_ = { aw_.h.y, aw_.h.y };                                         \
    f16x2 d0_ = un01 - u2h(q_.x);                                             \
    f16x2 d1_ = un23 - u2h(q_.y);                                             \
    f16x2 r0_ = __builtin_elementwise_max(a2_ * d0_, zz);                     \
    f16x2 r1_ = __builtin_elementwise_max(a2_ * d1_, zz);                     \
    acc01 = a2_ * r0_ + acc01;                                                \
    acc23 = a2_ * r1_ + acc23;                                                \
}
#define PROC(REG, TT) PROCW((uint32_t)__shfl((int)(REG), (TT) + g, 64))

// pure gather: one node per wave; writes scaled s (f16 x64 channels = 128B/node)
__launch_bounds__(256)
__global__ void k_gather_s(const int* __restrict__ rowptr, const uint32_t* __restrict__ adjp,
                           const _Float16* __restrict__ ucur, uint2* __restrict__ sout) {
    int wv = threadIdx.x >> 6, lane = threadIdx.x & 63;
    int g = lane >> 4, li = lane & 15;
    const uint2* upv = (const uint2*)ucur;
    int n = blockIdx.x * 4 + wv;          // 12500*4 == NN exactly
    uint2 unq = upv[n * 16 + li];
    f16x2 un01 = u2h(unq.x), un23 = u2h(unq.y);
    int k0 = rowptr[n], k1 = rowptr[n + 1];
    int deg = k1 - k0;
    // stage up to 128 entries with 2 coalesced loads (OOB lanes -> 0: weight 0, harmless)
    uint32_t a0r = (lane < deg) ? adjp[k0 + lane] : 0u;
    uint32_t a1r = (64 + lane < deg) ? adjp[k0 + 64 + lane] : 0u;
    f16x2 zz = { (_Float16)0.f, (_Float16)0.f };
    f16x2 acc01 = zz, acc23 = zz;
    int c1 = deg < 64 ? deg : 64;
    for (int t = 0; t < c1; t += 16) { PROC(a0r, t) PROC(a0r, t + 4) PROC(a0r, t + 8) PROC(a0r, t + 12) }
    if (deg > 64) {
        int c2 = deg - 64; if (c2 > 64) c2 = 64;
        for (int t = 0; t < c2; t += 16) { PROC(a1r, t) PROC(a1r, t + 4) PROC(a1r, t + 8) PROC(a1r, t + 12) }
    }
    if (deg > 128) {                      // rare tail
        for (int k = k0 + 128; k < k1; k += 4) {
            uint32_t wt = (k + g < k1) ? adjp[k + g] : 0u;
            PROCW(wt)
        }
    }
    // reduce across the 4 groups (lane bits 4,5)
    acc01 = acc01 + u2h((uint32_t)__shfl_xor((int)h2u(acc01), 16, 64));
    acc01 = acc01 + u2h((uint32_t)__shfl_xor((int)h2u(acc01), 32, 64));
    acc23 = acc23 + u2h((uint32_t)__shfl_xor((int)h2u(acc23), 16, 64));
    acc23 = acc23 + u2h((uint32_t)__shfl_xor((int)h2u(acc23), 32, 64));
    if (g == 0) sout[n * 16 + li] = make_uint2(h2u(acc01), h2u(acc23));
}

// ---- update (streaming): unext = ucur - c*M2*s ; sacc (+)= s ----
__launch_bounds__(256)
__global__ void k_update(const _Float16* __restrict__ ucur, const _Float16* __restrict__ s,
                         const float* __restrict__ M2s, float* __restrict__ sacc,
                         _Float16* __restrict__ unext, int beta) {
    __shared__ float sM[C * C];
    for (int idx = threadIdx.x; idx < C * C; idx += 256) sM[idx] = M2s[idx];
    __syncthreads();
    int wv = threadIdx.x >> 6, lane = threadIdx.x & 63;
    int n = blockIdx.x * 4 + wv;
    float sv = (float)s[(size_t)n * C + lane];
    float du = 0.f;
#pragma unroll
    for (int p = 0; p < C; p++)
        du = fmaf(sM[p * C + lane], __shfl(sv, p, 64), du);
    unext[(size_t)n * C + lane] = (_Float16)((float)ucur[(size_t)n * C + lane] - (DTH / SDIV) * du);
    size_t ix = (size_t)n * C + lane;
    sacc[ix] = beta ? (sacc[ix] + sv) : sv;
}

// ---- close: stot = sacc + s3; xf = x0 - c*KN1^T*stot; KNclose + log_softmax ----
__launch_bounds__(256)
__global__ void k_close(const _Float16* __restrict__ s3, const float* __restrict__ sacc,
                        const float* __restrict__ KN1, const float* __restrict__ KNcT,
                        const float* __restrict__ x, float* __restrict__ out) {
    __shared__ float sM[C * C];    // raw KN1: dx[o] = sum_p KN1[p,o]*stot[p]
    __shared__ float sKc[C * C];
    for (int idx = threadIdx.x; idx < C * C; idx += 256) { sM[idx] = KN1[idx]; sKc[idx] = KNcT[idx]; }
    __syncthreads();
    int wv = threadIdx.x >> 6, lane = threadIdx.x & 63;
    int n = blockIdx.x * 4 + wv;
    float stot = (float)s3[(size_t)n * C + lane] + sacc[(size_t)n * C + lane];
    float dx = 0.f;
#pragma unroll
    for (int p = 0; p < C; p++)
        dx = fmaf(sM[p * C + lane], __shfl(stot, p, 64), dx);
    float xf = x[(size_t)n * C + lane] - (DTH / SDIV) * dx;
    float o = 0.f;
#pragma unroll
    for (int i = 0; i < C; i++)
        o = fmaf(sKc[i * C + lane], __shfl(xf, i, 64), o);
    float m = o;
#pragma unroll
    for (int off2 = 32; off2; off2 >>= 1) m = fmaxf(m, __shfl_xor(m, off2, 64));
    float sum = expf(o - m);
#pragma unroll
    for (int off2 = 32; off2; off2 >>= 1) sum += __shfl_xor(sum, off2, 64);
    out[(size_t)n * C + lane] = o - m - logf(sum);
}

extern "C" void kernel_launch(void* const* d_in, const int* in_sizes, int n_in,
                              void* d_out, int out_size, void* d_ws, size_t ws_size,
                              hipStream_t stream) {
    (void)in_sizes; (void)n_in; (void)out_size; (void)ws_size;
    const float* xn   = (const float*)d_in[0];
    const int* iInd   = (const int*)d_in[1];
    const int* jInd   = (const int*)d_in[2];
    // d_in[3] = n_nodes scalar (fixed 50000)
    const float* K1   = (const float*)d_in[4];
    const float* KN1  = (const float*)d_in[5];
    const float* KNc  = (const float*)d_in[6];
    float* out = (float*)d_out;

    char* base = (char*)d_ws;
    size_t off = 0;
    auto alloc = [&](size_t bytes) { char* p = base + off; off = (off + bytes + 255) & ~(size_t)255; return p; };
    float* KN1T = (float*)alloc(C * C * 4);
    float* KNcT = (float*)alloc(C * C * 4);
    float* K1T  = (float*)alloc(NIN * C * 4);
    float* M2s  = (float*)alloc(C * C * 4);
    unsigned* pk = (unsigned*)alloc(NN * 4);
    int* rowptr = (int*)alloc((NN + 1) * 4);
    int* cursor = (int*)alloc(NN * 4);
    float* dinv = (float*)alloc(NN * 4);
    float* x    = (float*)alloc((size_t)NN * C * 4);       // 12.8 MB
    float* sacc = (float*)alloc((size_t)NN * C * 4);       // 12.8 MB
    _Float16* ua = (_Float16*)alloc((size_t)NN * C * 2);   // 6.4 MB
    _Float16* ub = (_Float16*)alloc((size_t)NN * C * 2);   // 6.4 MB
    _Float16* sb = (_Float16*)alloc((size_t)NN * C * 2);   // 6.4 MB
    uint32_t* adjp = (uint32_t*)alloc((size_t)2 * NE * 4); // 12.8 MB

    // prolog
    k_setup<<<1, 256, 0, stream>>>(KN1, KNc, K1, KN1T, KNcT, K1T, M2s);
    k_init_pk<<<(NN + 255) / 256, 256, 0, stream>>>(pk);
    k_count<<<NE / 256, 256, 0, stream>>>(iInd, jInd, pk);
    k_dinv<<<(NN + 255) / 256, 256, 0, stream>>>(pk, dinv);
    k_scan<<<1, 1024, 0, stream>>>(pk, rowptr, cursor);
    k_fill2<<<8 * PB, 256, 0, stream>>>(iInd, jInd, dinv, cursor, adjp);

    // opening + u0
    k_open_u<<<NN / 4, 256, 0, stream>>>(xn, K1T, KN1T, x, ua);

    const int GB = NN / 4;    // 12500 blocks, one node per wave
    // layer 0
    k_gather_s<<<GB, 256, 0, stream>>>(rowptr, adjp, ua, (uint2*)sb);
    k_update<<<GB, 256, 0, stream>>>(ua, sb, M2s, sacc, ub, 0);
    // layer 1
    k_gather_s<<<GB, 256, 0, stream>>>(rowptr, adjp, ub, (uint2*)sb);
    k_update<<<GB, 256, 0, stream>>>(ub, sb, M2s, sacc, ua, 1);
    // layer 2
    k_gather_s<<<GB, 256, 0, stream>>>(rowptr, adjp, ua, (uint2*)sb);
    k_update<<<GB, 256, 0, stream>>>(ua, sb, M2s, sacc, ub, 1);
    // layer 3 + close
    k_gather_s<<<GB, 256, 0, stream>>>(rowptr, adjp, ub, (uint2*)sb);
    k_close<<<GB, 256, 0, stream>>>(sb, sacc, KN1, KNcT, x, out);
}